// Round 2
// baseline (1320.085 us; speedup 1.0000x reference)
//
#include <hip/hip_runtime.h>
#include <hip/hip_bf16.h>
#include <stdint.h>

// Problem constants
#define BB 4
#define TT 2048
#define DD 1024
#define HH 16
#define HDD 64
// derived
#define M1 (BB*TT)      // 8192 rows
#define N1 (3*DD)       // 3072
#define KDIM DD         // 1024

typedef __attribute__((ext_vector_type(8))) short short8;   // 8 bf16 MFMA operand
typedef __attribute__((ext_vector_type(4))) float f32x4;

__device__ __forceinline__ float bf2f(unsigned short u) {
    union { uint32_t u32; float f; } c; c.u32 = ((uint32_t)u) << 16; return c.f;
}
__device__ __forceinline__ unsigned short f2bf(float f) {
    union { float f; uint32_t u32; } c; c.f = f;
    uint32_t u = c.u32;
    return (unsigned short)((u + 0x7FFFu + ((u >> 16) & 1u)) >> 16);  // RNE
}

// ---------------- elementwise fp32 -> bf16 (x), 4 elems/thread ----------------
__global__ __launch_bounds__(256) void cvt_f32_bf16(
    const float* __restrict__ in, unsigned short* __restrict__ out, int n4)
{
    int i = blockIdx.x * 256 + threadIdx.x;
    if (i >= n4) return;
    float4 v = *(const float4*)&in[(size_t)i * 4];
    ushort4 o;
    o.x = f2bf(v.x); o.y = f2bf(v.y); o.z = f2bf(v.z); o.w = f2bf(v.w);
    *(ushort4*)&out[(size_t)i * 4] = o;
}

// ---------------- transpose+convert: in fp32 [R][C] -> out bf16 [C][R] ----------------
__global__ __launch_bounds__(256) void transpose_f32_bf16(
    const float* __restrict__ in, unsigned short* __restrict__ out,
    int R, int C)
{
    __shared__ unsigned short tile[32][33];
    int bx = blockIdx.x;  // over C/32
    int by = blockIdx.y;  // over R/32
    int x = bx*32 + threadIdx.x;
    int y0 = by*32 + threadIdx.y;
    #pragma unroll
    for (int i = 0; i < 32; i += 8)
        tile[threadIdx.y + i][threadIdx.x] = f2bf(in[(size_t)(y0 + i)*C + x]);
    __syncthreads();
    int xo = by*32 + threadIdx.x;   // out col = orig row
    int yo = bx*32 + threadIdx.y;   // out row = orig col
    #pragma unroll
    for (int i = 0; i < 32; i += 8)
        out[(size_t)(yo + i)*R + xo] = tile[threadIdx.x][threadIdx.y + i];
}

// ---------------- MFMA bf16 GEMM: C[M][N] = A[M][K] @ B + bias(f32), B given as BT[N][K] ----------------
// 128x128 tile, BK=32, 256 threads = 4 waves (2x2), each wave 64x64 = 4x4 mfma_16x16x32 tiles.
// OUT_F32: write fp32 (final output) vs bf16 (intermediate).
template <bool OUT_F32>
__global__ __launch_bounds__(256) void gemm_bf16_mfma(
    const unsigned short* __restrict__ A, const unsigned short* __restrict__ BT,
    const float* __restrict__ bias, void* __restrict__ Cout,
    int M, int N, int K)
{
    __shared__ unsigned short As[128*32];
    __shared__ unsigned short Bs[128*32];
    const int tid  = threadIdx.x;
    const int lane = tid & 63;
    const int wave = tid >> 6;
    const int wm = wave >> 1, wn = wave & 1;
    const int quad = lane >> 4, l16 = lane & 15;
    const int m0 = blockIdx.y * 128, n0 = blockIdx.x * 128;

    f32x4 acc[4][4] = {};

    const int nk = K >> 5;
    for (int kt = 0; kt < nk; ++kt) {
        const int k0 = kt << 5;
        __syncthreads();
        // stage: 512 chunks of 8 bf16 per matrix; chunk c: row=c>>2, seg=c&3
        #pragma unroll
        for (int h = 0; h < 2; ++h) {
            int c = tid + h*256;
            int row = c >> 2, seg = c & 3;
            uint4 va = *(const uint4*)&A[(size_t)(m0 + row)*K + k0 + seg*8];
            *(uint4*)&As[row*32 + seg*8] = va;
            uint4 vb = *(const uint4*)&BT[(size_t)(n0 + row)*K + k0 + seg*8];
            *(uint4*)&Bs[row*32 + seg*8] = vb;
        }
        __syncthreads();
        short8 af[4], bf[4];
        #pragma unroll
        for (int mi = 0; mi < 4; ++mi)
            af[mi] = *(short8*)&As[(wm*64 + mi*16 + l16)*32 + quad*8];
        #pragma unroll
        for (int ni = 0; ni < 4; ++ni)
            bf[ni] = *(short8*)&Bs[(wn*64 + ni*16 + l16)*32 + quad*8];
        #pragma unroll
        for (int mi = 0; mi < 4; ++mi)
            #pragma unroll
            for (int ni = 0; ni < 4; ++ni)
                acc[mi][ni] = __builtin_amdgcn_mfma_f32_16x16x32_bf16(
                    af[mi], bf[ni], acc[mi][ni], 0, 0, 0);
    }

    // epilogue: D[m][n], m=(lane>>4)*4+reg, n=lane&15 within each 16x16 tile
    #pragma unroll
    for (int ni = 0; ni < 4; ++ni) {
        int n = n0 + wn*64 + ni*16 + l16;
        float bv = bias[n];
        #pragma unroll
        for (int mi = 0; mi < 4; ++mi) {
            #pragma unroll
            for (int r = 0; r < 4; ++r) {
                int m = m0 + wm*64 + mi*16 + quad*4 + r;
                float val = acc[mi][ni][r] + bv;
                if (OUT_F32)
                    ((float*)Cout)[(size_t)m*N + n] = val;
                else
                    ((unsigned short*)Cout)[(size_t)m*N + n] = f2bf(val);
            }
        }
    }
}

// ---------------- flash attention (VALU, fp32 in LDS), bf16 QKV in / bf16 Y out ----------------
// grid: (T/64, B*H). block 256. Each block: 64 queries of one (b,h).
// Thread (qy=t>>4, tx=t&15) owns S/O 4x4 block: rows q=qy*4.., cols (k or d)=tx*4..
__global__ __launch_bounds__(256) void attn_kernel(
    const unsigned short* __restrict__ QKV, unsigned short* __restrict__ Y)
{
    __shared__ float Qs[64*64];   // [d][q]  (transposed)
    __shared__ float Ks[64*64];   // [d][k]  (transposed)
    __shared__ float Vs[64*68];   // [k][d]  (padded stride 68)
    __shared__ float Ps[64*68];   // [k][q]  (padded stride 68)

    const int tid = threadIdx.x;
    const int tx = tid & 15;
    const int qy = tid >> 4;
    const int qt = blockIdx.x;
    const int bh = blockIdx.y;
    const int b = bh >> 4, h = bh & 15;
    const int q0 = qt * 64;
    const int rowstride = 3*DD;
    const size_t rowbase = (size_t)(b*TT) * rowstride;
    const int qcol = h*HDD, kcol = DD + h*HDD, vcol = 2*DD + h*HDD;
    const float scale = 0.125f;   // 1/sqrt(64)

    // stage Q (scaled) transposed: chunk c: q=c&63, dc=c>>6
    #pragma unroll
    for (int hh = 0; hh < 2; ++hh) {
        int c = tid + hh*256;
        int q = c & 63, dc = c >> 6;
        uint4 v = *(const uint4*)&QKV[rowbase + (size_t)(q0+q)*rowstride + qcol + dc*8];
        const unsigned short* u = (const unsigned short*)&v;
        #pragma unroll
        for (int j = 0; j < 8; ++j)
            Qs[(dc*8+j)*64 + q] = bf2f(u[j]) * scale;
    }

    float o[4][4] = {};
    float mrow[4], lrow[4];
    #pragma unroll
    for (int i = 0; i < 4; ++i) { mrow[i] = -1e30f; lrow[i] = 0.0f; }

    for (int kt = 0; kt <= qt; ++kt) {
        const int k0 = kt * 64;
        __syncthreads();  // prev tile's reads of Ks/Vs done (also covers Qs staging at kt=0)
        // stage K transposed: [d][k]
        #pragma unroll
        for (int hh = 0; hh < 2; ++hh) {
            int c = tid + hh*256;
            int k = c & 63, dc = c >> 6;
            uint4 v = *(const uint4*)&QKV[rowbase + (size_t)(k0+k)*rowstride + kcol + dc*8];
            const unsigned short* u = (const unsigned short*)&v;
            #pragma unroll
            for (int j = 0; j < 8; ++j)
                Ks[(dc*8+j)*64 + k] = bf2f(u[j]);
        }
        // stage V natural: [k][d] stride 68
        #pragma unroll
        for (int hh = 0; hh < 2; ++hh) {
            int c = tid + hh*256;
            int k = c >> 3, dc = c & 7;
            uint4 v = *(const uint4*)&QKV[rowbase + (size_t)(k0+k)*rowstride + vcol + dc*8];
            const unsigned short* u = (const unsigned short*)&v;
            #pragma unroll
            for (int j = 0; j < 8; ++j)
                Vs[k*68 + dc*8 + j] = bf2f(u[j]);
        }
        __syncthreads();

        // scores: S = (Q*scale) @ K^T, outer-product over d
        float s[4][4] = {};
        for (int d = 0; d < 64; ++d) {
            f32x4 qv = *(f32x4*)&Qs[d*64 + qy*4];
            f32x4 kv = *(f32x4*)&Ks[d*64 + tx*4];
            #pragma unroll
            for (int i = 0; i < 4; ++i)
                #pragma unroll
                for (int j = 0; j < 4; ++j)
                    s[i][j] = fmaf(qv[i], kv[j], s[i][j]);
        }
        if (kt == qt) {  // causal mask inside diagonal tile
            #pragma unroll
            for (int i = 0; i < 4; ++i)
                #pragma unroll
                for (int j = 0; j < 4; ++j)
                    if (tx*4 + j > qy*4 + i) s[i][j] = -1e30f;
        }

        // online softmax, per-row stats via in-wave shuffles (16 lanes share a row group)
        float alpha[4];
        #pragma unroll
        for (int i = 0; i < 4; ++i) {
            float rmax = fmaxf(fmaxf(s[i][0], s[i][1]), fmaxf(s[i][2], s[i][3]));
            #pragma unroll
            for (int off = 1; off < 16; off <<= 1)
                rmax = fmaxf(rmax, __shfl_xor(rmax, off, 64));
            float mnew = fmaxf(mrow[i], rmax);
            alpha[i] = __expf(mrow[i] - mnew);
            float rs = 0.0f;
            #pragma unroll
            for (int j = 0; j < 4; ++j) {
                float p = __expf(s[i][j] - mnew);
                s[i][j] = p;
                rs += p;
            }
            #pragma unroll
            for (int off = 1; off < 16; off <<= 1)
                rs += __shfl_xor(rs, off, 64);
            lrow[i] = lrow[i]*alpha[i] + rs;
            mrow[i] = mnew;
        }
        // write P transposed [k][q]; writer lanes and reader lanes share a wave (same qy group)
        #pragma unroll
        for (int i = 0; i < 4; ++i)
            #pragma unroll
            for (int j = 0; j < 4; ++j)
                Ps[(tx*4+j)*68 + qy*4 + i] = s[i][j];

        // O = O*alpha + P @ V
        #pragma unroll
        for (int i = 0; i < 4; ++i)
            #pragma unroll
            for (int j = 0; j < 4; ++j)
                o[i][j] *= alpha[i];
        for (int k = 0; k < 64; ++k) {
            f32x4 pv = *(f32x4*)&Ps[k*68 + qy*4];
            f32x4 vv = *(f32x4*)&Vs[k*68 + tx*4];
            #pragma unroll
            for (int i = 0; i < 4; ++i)
                #pragma unroll
                for (int j = 0; j < 4; ++j)
                    o[i][j] = fmaf(pv[i], vv[j], o[i][j]);
        }
    }

    // normalize + store Y[b, t, h*64+d] as bf16
    #pragma unroll
    for (int i = 0; i < 4; ++i) {
        float inv = 1.0f / lrow[i];
        int trow = q0 + qy*4 + i;
        ushort4 pack;
        pack.x = f2bf(o[i][0] * inv);
        pack.y = f2bf(o[i][1] * inv);
        pack.z = f2bf(o[i][2] * inv);
        pack.w = f2bf(o[i][3] * inv);
        *(ushort4*)&Y[((size_t)(b*TT + trow))*DD + h*HDD + tx*4] = pack;
    }
}

extern "C" void kernel_launch(void* const* d_in, const int* in_sizes, int n_in,
                              void* d_out, int out_size, void* d_ws, size_t ws_size,
                              hipStream_t stream)
{
    const float* x    = (const float*)d_in[0];   // [4,2048,1024] fp32
    // d_in[1] = causal_mask (int32) — causality implemented analytically, unused
    const float* wqkv = (const float*)d_in[2];   // [1024][3072] fp32
    const float* bqkv = (const float*)d_in[3];   // [3072] fp32
    const float* wout = (const float*)d_in[4];   // [1024][1024] fp32
    const float* bout = (const float*)d_in[5];   // [1024] fp32
    float* out = (float*)d_out;                  // [4,2048,1024] fp32

    char* ws = (char*)d_ws;
    unsigned short* Xb    = (unsigned short*)ws;                    // 8192*1024 bf16 = 16 MB
    unsigned short* WqkvT = (unsigned short*)(ws + 16777216);       // 3072*1024 bf16 = 6 MB
    unsigned short* WoutT = (unsigned short*)(ws + 23068672);       // 1024*1024 bf16 = 2 MB
    unsigned short* QKV   = (unsigned short*)(ws + 25165824);       // 8192*3072 bf16 = 48 MB
    unsigned short* Ybuf  = (unsigned short*)(ws + 75497472);       // 8192*1024 bf16 = 16 MB
                                                                    // total 88 MB

    // 1. convert x to bf16; transpose+convert weights to bf16 [N][K]
    cvt_f32_bf16<<<(M1*KDIM/4 + 255)/256, 256, 0, stream>>>(x, Xb, M1*KDIM/4);
    transpose_f32_bf16<<<dim3(N1/32, KDIM/32), dim3(32, 8), 0, stream>>>(wqkv, WqkvT, KDIM, N1);
    transpose_f32_bf16<<<dim3(DD/32, KDIM/32), dim3(32, 8), 0, stream>>>(wout, WoutT, KDIM, DD);
    // 2. QKV projection: [8192,1024] @ [1024,3072] + b  -> bf16
    gemm_bf16_mfma<false><<<dim3(N1/128, M1/128), 256, 0, stream>>>(Xb, WqkvT, bqkv, QKV, M1, N1, KDIM);
    // 3. causal flash attention per (b,h), 64-query tiles -> bf16
    attn_kernel<<<dim3(TT/64, BB*HH), 256, 0, stream>>>(QKV, Ybuf);
    // 4. output projection: [8192,1024] @ [1024,1024] + b -> fp32 out
    gemm_bf16_mfma<true><<<dim3(DD/128, M1/128), 256, 0, stream>>>(Ybuf, WoutT, bout, out, M1, DD, KDIM);
}

// Round 3
// 497.071 us; speedup vs baseline: 2.6557x; 2.6557x over previous
//
#include <hip/hip_runtime.h>
#include <hip/hip_bf16.h>
#include <stdint.h>

// Problem constants
#define BB 4
#define TT 2048
#define DD 1024
#define HH 16
#define HDD 64
// derived
#define M1 (BB*TT)      // 8192 rows
#define N1 (3*DD)       // 3072
#define KDIM DD         // 1024

typedef __attribute__((ext_vector_type(8))) short short8;   // 8 bf16 MFMA operand
typedef __attribute__((ext_vector_type(4))) float f32x4;

#if __has_builtin(__builtin_amdgcn_exp2f)
#define EXP2(x) __builtin_amdgcn_exp2f(x)
#else
#define EXP2(x) exp2f(x)
#endif

__device__ __forceinline__ float bf2f(unsigned short u) {
    union { uint32_t u32; float f; } c; c.u32 = ((uint32_t)u) << 16; return c.f;
}
__device__ __forceinline__ unsigned short f2bf(float f) {
    union { float f; uint32_t u32; } c; c.f = f;
    uint32_t u = c.u32;
    return (unsigned short)((u + 0x7FFFu + ((u >> 16) & 1u)) >> 16);  // RNE
}

// ---------------- elementwise fp32 -> bf16 (x), 4 elems/thread ----------------
__global__ __launch_bounds__(256) void cvt_f32_bf16(
    const float* __restrict__ in, unsigned short* __restrict__ out, int n4)
{
    int i = blockIdx.x * 256 + threadIdx.x;
    if (i >= n4) return;
    float4 v = *(const float4*)&in[(size_t)i * 4];
    ushort4 o;
    o.x = f2bf(v.x); o.y = f2bf(v.y); o.z = f2bf(v.z); o.w = f2bf(v.w);
    *(ushort4*)&out[(size_t)i * 4] = o;
}

// ---------------- transpose+convert: in fp32 [R][C] -> out bf16 [C][R] ----------------
__global__ __launch_bounds__(256) void transpose_f32_bf16(
    const float* __restrict__ in, unsigned short* __restrict__ out,
    int R, int C)
{
    __shared__ unsigned short tile[32][33];
    int bx = blockIdx.x;
    int by = blockIdx.y;
    int x = bx*32 + threadIdx.x;
    int y0 = by*32 + threadIdx.y;
    #pragma unroll
    for (int i = 0; i < 32; i += 8)
        tile[threadIdx.y + i][threadIdx.x] = f2bf(in[(size_t)(y0 + i)*C + x]);
    __syncthreads();
    int xo = by*32 + threadIdx.x;
    int yo = bx*32 + threadIdx.y;
    #pragma unroll
    for (int i = 0; i < 32; i += 8)
        out[(size_t)(yo + i)*R + xo] = tile[threadIdx.x][threadIdx.y + i];
}

// ---------------- MFMA bf16 GEMM (unchanged, passing) ----------------
template <bool OUT_F32>
__global__ __launch_bounds__(256) void gemm_bf16_mfma(
    const unsigned short* __restrict__ A, const unsigned short* __restrict__ BT,
    const float* __restrict__ bias, void* __restrict__ Cout,
    int M, int N, int K)
{
    __shared__ unsigned short As[128*32];
    __shared__ unsigned short Bs[128*32];
    const int tid  = threadIdx.x;
    const int lane = tid & 63;
    const int wave = tid >> 6;
    const int wm = wave >> 1, wn = wave & 1;
    const int quad = lane >> 4, l16 = lane & 15;
    const int m0 = blockIdx.y * 128, n0 = blockIdx.x * 128;

    f32x4 acc[4][4] = {};

    const int nk = K >> 5;
    for (int kt = 0; kt < nk; ++kt) {
        const int k0 = kt << 5;
        __syncthreads();
        #pragma unroll
        for (int h = 0; h < 2; ++h) {
            int c = tid + h*256;
            int row = c >> 2, seg = c & 3;
            uint4 va = *(const uint4*)&A[(size_t)(m0 + row)*K + k0 + seg*8];
            *(uint4*)&As[row*32 + seg*8] = va;
            uint4 vb = *(const uint4*)&BT[(size_t)(n0 + row)*K + k0 + seg*8];
            *(uint4*)&Bs[row*32 + seg*8] = vb;
        }
        __syncthreads();
        short8 af[4], bf[4];
        #pragma unroll
        for (int mi = 0; mi < 4; ++mi)
            af[mi] = *(short8*)&As[(wm*64 + mi*16 + l16)*32 + quad*8];
        #pragma unroll
        for (int ni = 0; ni < 4; ++ni)
            bf[ni] = *(short8*)&Bs[(wn*64 + ni*16 + l16)*32 + quad*8];
        #pragma unroll
        for (int mi = 0; mi < 4; ++mi)
            #pragma unroll
            for (int ni = 0; ni < 4; ++ni)
                acc[mi][ni] = __builtin_amdgcn_mfma_f32_16x16x32_bf16(
                    af[mi], bf[ni], acc[mi][ni], 0, 0, 0);
    }

    #pragma unroll
    for (int ni = 0; ni < 4; ++ni) {
        int n = n0 + wn*64 + ni*16 + l16;
        float bv = bias[n];
        #pragma unroll
        for (int mi = 0; mi < 4; ++mi) {
            #pragma unroll
            for (int r = 0; r < 4; ++r) {
                int m = m0 + wm*64 + mi*16 + quad*4 + r;
                float val = acc[mi][ni][r] + bv;
                if (OUT_F32)
                    ((float*)Cout)[(size_t)m*N + n] = val;
                else
                    ((unsigned short*)Cout)[(size_t)m*N + n] = f2bf(val);
            }
        }
    }
}

// ---------------- MFMA flash attention ----------------
// grid: (16, B*H), block 256 = 4 waves. Q-tile 128 rows (wave owns 32 = 2 m-tiles),
// K-tile 64. All LDS tiles stride 72 shorts (144 B: 16B-aligned rows, conflict-free
// b128 fragment reads). V staged transposed [d][k] so PV's B-operand reads are the
// verified "BT row-major" pattern. Softmax in exp2 domain (scale*log2e folded into
// the per-element FMA). P round-trips LDS bf16; writer wave == reader wave.
#define PSTR 72
__global__ __launch_bounds__(256, 2) void attn_mfma(
    const unsigned short* __restrict__ QKV, unsigned short* __restrict__ Y)
{
    __shared__ __align__(16) unsigned short Qs[128*PSTR];
    __shared__ __align__(16) unsigned short Ks[64*PSTR];
    __shared__ __align__(16) unsigned short Vt[64*PSTR];   // [d][k]
    __shared__ __align__(16) unsigned short Ps[128*PSTR];

    const int tid  = threadIdx.x;
    const int lane = tid & 63, wave = tid >> 6;
    const int quad = lane >> 4, l16 = lane & 15;
    const int qt = (gridDim.x - 1) - blockIdx.x;   // big causal blocks dispatch first
    const int bh = blockIdx.y;
    const int b = bh >> 4, h = bh & 15;
    const int q0 = qt * 128;
    const int q0w = q0 + wave*32;
    const size_t rowbase = (size_t)(b*TT) * 3072;
    const int qcol = h*64, kcol = 1024 + h*64, vcol = 2048 + h*64;
    const float C2 = 0.18033688011112042f;   // (1/sqrt(64)) * log2(e)

    // ---- stage Q: 128 rows x 64 cols (1024 uint4 chunks, 4/thread)
    #pragma unroll
    for (int hh = 0; hh < 4; ++hh) {
        int c = tid + hh*256;
        int row = c >> 3, dc = c & 7;
        uint4 v = *(const uint4*)&QKV[rowbase + (size_t)(q0+row)*3072 + qcol + dc*8];
        *(uint4*)&Qs[row*PSTR + dc*8] = v;
    }
    __syncthreads();

    // Q fragments held in registers for the whole k-loop
    short8 aq[2][2];
    #pragma unroll
    for (int mt = 0; mt < 2; ++mt)
        #pragma unroll
        for (int kk = 0; kk < 2; ++kk)
            aq[mt][kk] = *(short8*)&Qs[(wave*32 + mt*16 + l16)*PSTR + kk*32 + quad*8];

    f32x4 o[2][4] = {};
    float mold[2][4], lsum[2][4];
    #pragma unroll
    for (int mt = 0; mt < 2; ++mt)
        #pragma unroll
        for (int r = 0; r < 4; ++r) { mold[mt][r] = -3.0e38f; lsum[mt][r] = 0.0f; }

    const int nkt = 2*qt + 2;

    // register-prefetch K/V tile 0
    uint4 kr[2], vr[2];
    {
        #pragma unroll
        for (int hh = 0; hh < 2; ++hh) {
            int c = tid + hh*256;
            int row = c >> 3, dc = c & 7;
            kr[hh] = *(const uint4*)&QKV[rowbase + (size_t)(row)*3072 + kcol + dc*8];
            vr[hh] = *(const uint4*)&QKV[rowbase + (size_t)(row)*3072 + vcol + dc*8];
        }
    }

    for (int kt = 0; kt < nkt; ++kt) {
        const int k0 = kt * 64;
        __syncthreads();   // prior iteration's Ks/Vt reads complete
        // write staged regs -> LDS
        #pragma unroll
        for (int hh = 0; hh < 2; ++hh) {
            int c = tid + hh*256;
            int row = c >> 3, dc = c & 7;
            *(uint4*)&Ks[row*PSTR + dc*8] = kr[hh];
            const unsigned short* vp = (const unsigned short*)&vr[hh];
            #pragma unroll
            for (int j = 0; j < 8; ++j)
                Vt[(dc*8 + j)*PSTR + row] = vp[j];   // transpose (known ~8-way wr conflict)
        }
        // prefetch next tile (clamped; redundant reload on last iter, avoids UB)
        {
            const int knx = (kt+1 < nkt ? kt+1 : kt) * 64;
            #pragma unroll
            for (int hh = 0; hh < 2; ++hh) {
                int c = tid + hh*256;
                int row = c >> 3, dc = c & 7;
                kr[hh] = *(const uint4*)&QKV[rowbase + (size_t)(knx+row)*3072 + kcol + dc*8];
                vr[hh] = *(const uint4*)&QKV[rowbase + (size_t)(knx+row)*3072 + vcol + dc*8];
            }
        }
        __syncthreads();   // staging visible

        const bool skip = (k0 > q0w + 31);   // wave-uniform: tile fully above diagonal
        if (skip) continue;

        // ---- S = Q K^T
        f32x4 s[2][4] = {};
        #pragma unroll
        for (int kk = 0; kk < 2; ++kk)
            #pragma unroll
            for (int nt = 0; nt < 4; ++nt) {
                short8 bk = *(short8*)&Ks[(nt*16 + l16)*PSTR + kk*32 + quad*8];
                s[0][nt] = __builtin_amdgcn_mfma_f32_16x16x32_bf16(aq[0][kk], bk, s[0][nt], 0, 0, 0);
                s[1][nt] = __builtin_amdgcn_mfma_f32_16x16x32_bf16(aq[1][kk], bk, s[1][nt], 0, 0, 0);
            }

        // ---- causal mask (only tiles straddling the diagonal)
        if (k0 + 63 > q0w) {
            #pragma unroll
            for (int mt = 0; mt < 2; ++mt)
                #pragma unroll
                for (int nt = 0; nt < 4; ++nt)
                    #pragma unroll
                    for (int r = 0; r < 4; ++r) {
                        int kg = k0 + nt*16 + l16;
                        int qg = q0w + mt*16 + quad*4 + r;
                        if (kg > qg) s[mt][nt][r] = -3.0e38f;
                    }
        }

        // ---- online softmax in exp2 domain
        float m2n[2][4], al[2][4];
        #pragma unroll
        for (int mt = 0; mt < 2; ++mt)
            #pragma unroll
            for (int r = 0; r < 4; ++r) {
                float rm = fmaxf(fmaxf(s[mt][0][r], s[mt][1][r]),
                                 fmaxf(s[mt][2][r], s[mt][3][r]));
                rm = fmaxf(rm, __shfl_xor(rm, 1, 16));
                rm = fmaxf(rm, __shfl_xor(rm, 2, 16));
                rm = fmaxf(rm, __shfl_xor(rm, 4, 16));
                rm = fmaxf(rm, __shfl_xor(rm, 8, 16));
                float m2 = fmaxf(mold[mt][r], rm * C2);
                al[mt][r]  = EXP2(mold[mt][r] - m2);
                m2n[mt][r] = m2;
            }
        float rs[2][4] = {};
        #pragma unroll
        for (int mt = 0; mt < 2; ++mt)
            #pragma unroll
            for (int nt = 0; nt < 4; ++nt)
                #pragma unroll
                for (int r = 0; r < 4; ++r) {
                    float p = EXP2(fmaf(s[mt][nt][r], C2, -m2n[mt][r]));
                    s[mt][nt][r] = p;
                    rs[mt][r] += p;
                }
        #pragma unroll
        for (int mt = 0; mt < 2; ++mt)
            #pragma unroll
            for (int r = 0; r < 4; ++r) {
                float t = rs[mt][r];
                t += __shfl_xor(t, 1, 16);
                t += __shfl_xor(t, 2, 16);
                t += __shfl_xor(t, 4, 16);
                t += __shfl_xor(t, 8, 16);
                lsum[mt][r] = lsum[mt][r]*al[mt][r] + t;
                mold[mt][r] = m2n[mt][r];
            }

        // ---- P -> LDS bf16 (round-half-up; own rows only, no barrier needed)
        #pragma unroll
        for (int mt = 0; mt < 2; ++mt)
            #pragma unroll
            for (int nt = 0; nt < 4; ++nt)
                #pragma unroll
                for (int r = 0; r < 4; ++r) {
                    union { float f; uint32_t u; } c; c.f = s[mt][nt][r];
                    Ps[(wave*32 + mt*16 + quad*4 + r)*PSTR + nt*16 + l16] =
                        (unsigned short)((c.u + 0x8000u) >> 16);
                }

        // ---- O = O*alpha + P V
        #pragma unroll
        for (int mt = 0; mt < 2; ++mt)
            #pragma unroll
            for (int dt = 0; dt < 4; ++dt)
                #pragma unroll
                for (int r = 0; r < 4; ++r)
                    o[mt][dt][r] *= al[mt][r];
        #pragma unroll
        for (int kk = 0; kk < 2; ++kk) {
            short8 ap0 = *(short8*)&Ps[(wave*32 +      l16)*PSTR + kk*32 + quad*8];
            short8 ap1 = *(short8*)&Ps[(wave*32 + 16 + l16)*PSTR + kk*32 + quad*8];
            #pragma unroll
            for (int dt = 0; dt < 4; ++dt) {
                short8 bv = *(short8*)&Vt[(dt*16 + l16)*PSTR + kk*32 + quad*8];
                o[0][dt] = __builtin_amdgcn_mfma_f32_16x16x32_bf16(ap0, bv, o[0][dt], 0, 0, 0);
                o[1][dt] = __builtin_amdgcn_mfma_f32_16x16x32_bf16(ap1, bv, o[1][dt], 0, 0, 0);
            }
        }
    }

    // ---- normalize + store (bf16 intermediate Y)
    #pragma unroll
    for (int mt = 0; mt < 2; ++mt)
        #pragma unroll
        for (int r = 0; r < 4; ++r) {
            float inv = 1.0f / lsum[mt][r];
            int t = q0w + mt*16 + quad*4 + r;
            #pragma unroll
            for (int dt = 0; dt < 4; ++dt)
                Y[((size_t)(b*TT + t))*DD + h*64 + dt*16 + l16] = f2bf(o[mt][dt][r] * inv);
        }
}

extern "C" void kernel_launch(void* const* d_in, const int* in_sizes, int n_in,
                              void* d_out, int out_size, void* d_ws, size_t ws_size,
                              hipStream_t stream)
{
    const float* x    = (const float*)d_in[0];   // [4,2048,1024] fp32
    // d_in[1] = causal_mask (int32) — causality implemented analytically, unused
    const float* wqkv = (const float*)d_in[2];   // [1024][3072] fp32
    const float* bqkv = (const float*)d_in[3];   // [3072] fp32
    const float* wout = (const float*)d_in[4];   // [1024][1024] fp32
    const float* bout = (const float*)d_in[5];   // [1024] fp32
    float* out = (float*)d_out;                  // [4,2048,1024] fp32

    char* ws = (char*)d_ws;
    unsigned short* Xb    = (unsigned short*)ws;                    // 16 MB
    unsigned short* WqkvT = (unsigned short*)(ws + 16777216);       // 6 MB
    unsigned short* WoutT = (unsigned short*)(ws + 23068672);       // 2 MB
    unsigned short* QKV   = (unsigned short*)(ws + 25165824);       // 48 MB
    unsigned short* Ybuf  = (unsigned short*)(ws + 75497472);       // 16 MB

    cvt_f32_bf16<<<(M1*KDIM/4 + 255)/256, 256, 0, stream>>>(x, Xb, M1*KDIM/4);
    transpose_f32_bf16<<<dim3(N1/32, KDIM/32), dim3(32, 8), 0, stream>>>(wqkv, WqkvT, KDIM, N1);
    transpose_f32_bf16<<<dim3(DD/32, KDIM/32), dim3(32, 8), 0, stream>>>(wout, WoutT, KDIM, DD);
    gemm_bf16_mfma<false><<<dim3(N1/128, M1/128), 256, 0, stream>>>(Xb, WqkvT, bqkv, QKV, M1, N1, KDIM);
    attn_mfma<<<dim3(TT/128, BB*HH), 256, 0, stream>>>(QKV, Ybuf);
    gemm_bf16_mfma<true><<<dim3(DD/128, M1/128), 256, 0, stream>>>(Ybuf, WoutT, bout, out, M1, DD, KDIM);
}